// Round 16
// baseline (117.422 us; speedup 1.0000x reference)
//
#include <hip/hip_runtime.h>

// GraphUnetPool: scores = sigmoid(h@w+b); top-k (k=N/2) by exact rank-count;
// new_h = h[idx]*values; un_g = (g@g)[idx][:,idx] via per-row LDS counting over a
// FLAT per-row 2-hop rank list (rowlist) built edge-parallel (no latency chains).
// 8 nodes: [scores+zero+ones] -> [rank+hist] -> [select+scan] ->
//          [newh+scatter1+hist2] -> [scan2+rowlen] -> [scan3+scatter2] ->
//          [copy rowlist] -> [stream-paths].

typedef unsigned long long u64;
typedef unsigned int u32;
typedef float f32x4 __attribute__((ext_vector_type(4)));   // native vec for nt-store

__device__ __forceinline__ void nt_store4(float* p, float x, float y, float z, float w) {
    f32x4 v = { x, y, z, w };
    __builtin_nontemporal_store(v, (f32x4*)p);
}

// ---- node1: scores (1 wave/row) + zero rankcnt/deg/deg2 + edge_attr ones ----
__global__ void fused_scores(const float* __restrict__ h, const float* __restrict__ w,
                             const float* __restrict__ b, u64* __restrict__ keys,
                             int* __restrict__ zerobuf, float* __restrict__ ones_out,
                             int N, int n4) {
    int g = blockIdx.x * blockDim.x + threadIdx.x;
    if (g < 3 * N) zerobuf[g] = 0;              // rankcnt + deg + deg2 (adjacent)
    if (g < n4) nt_store4(ones_out + (size_t)g * 4, 1.f, 1.f, 1.f, 1.f);
    int wave = g >> 6;
    int lane = threadIdx.x & 63;
    if (wave >= N) return;
    const float4 a = ((const float4*)(h + (size_t)wave * 256))[lane];
    const float4 c = ((const float4*)w)[lane];
    float s = a.x * c.x + a.y * c.y + a.z * c.z + a.w * c.w;
    #pragma unroll
    for (int off = 32; off; off >>= 1) s += __shfl_xor(s, off);
    if (lane == 0) {
        s += b[0];
        float sc = 1.0f / (1.0f + expf(-s));
        keys[wave] = ((u64)__float_as_uint(sc) << 32) | (u32)(~wave);  // ties: lower idx
    }
}

// ---- node2: rank (1024-key LDS tiles, 1 elem/thread) + first-hop degree hist ----
__global__ void rank_hist(const u64* __restrict__ keys, int* __restrict__ rankcnt,
                          const int* __restrict__ ei0, int* __restrict__ deg,
                          int N, int E, int nrank) {
    __shared__ u64 lk[1024];
    int b = blockIdx.x, tid = threadIdx.x;
    if (b < nrank) {
        int ngroups = N >> 8;                   // element groups of 256
        int chunk = b / ngroups;                // 1024-key chunks
        int elg = b % ngroups;
        int base = chunk << 10;
        #pragma unroll
        for (int j = 0; j < 4; ++j) lk[tid + (j << 8)] = keys[base + tid + (j << 8)];
        __syncthreads();
        int el = (elg << 8) + tid;
        u64 mk = keys[el];
        int cnt = 0;
        #pragma unroll 16
        for (int i = 0; i < 1024; ++i) cnt += (lk[i] > mk) ? 1 : 0;
        atomicAdd(&rankcnt[el], cnt);
    } else {
        int e0 = ((b - nrank) << 10) + tid;     // 4 edges/thread
        #pragma unroll
        for (int j = 0; j < 4; ++j) {
            int e = e0 + (j << 8);
            if (e < E) atomicAdd(&deg[ei0[e]], 1);
        }
    }
}

// ---- node3: select (rank scatter, outputs idx/batch) + CSR exclusive scan ----
__global__ void select_scan(const u64* __restrict__ keys, const int* __restrict__ rankcnt,
                            const int* __restrict__ batch, int* __restrict__ idx_list,
                            float* __restrict__ val_list, int* __restrict__ rank,
                            float* __restrict__ out_idx, float* __restrict__ out_batch,
                            const int* __restrict__ deg, int* __restrict__ offs,
                            int* __restrict__ cursor, int N, int kN) {
    __shared__ int part[1024];
    int b = blockIdx.x, t = threadIdx.x;
    int nsel = N >> 10;                         // select blocks (1024 thr each)
    if (b < nsel) {
        int i = (b << 10) + t;
        int r = rankcnt[i];
        rank[i] = (r < kN) ? r : kN;
        if (r < kN) {
            idx_list[r] = i;
            val_list[r] = __uint_as_float((u32)(keys[i] >> 32));
            out_idx[r] = (float)i;
            out_batch[r] = (float)batch[i];
        }
    } else {
        int per = N >> 10;                      // 8 per thread
        int base = t * per;
        int loc[8];
        int s = 0;
        #pragma unroll
        for (int j = 0; j < 8; ++j) { if (j < per) { loc[j] = s; s += deg[base + j]; } }
        part[t] = s;
        __syncthreads();
        for (int d = 1; d < 1024; d <<= 1) {
            int v = (t >= d) ? part[t - d] : 0;
            __syncthreads();
            part[t] += v;
            __syncthreads();
        }
        int excl = (t == 0) ? 0 : part[t - 1];
        #pragma unroll
        for (int j = 0; j < 8; ++j) {
            if (j < per) { int o = excl + loc[j]; offs[base + j] = o; cursor[base + j] = o; }
        }
        if (t == 1023) offs[N] = part[1023];
    }
}

// ---- node4: new_h + scatter1 (nbr[p]=v) + filtered-degree hist2 ----
__global__ void newh_scatter(const float* __restrict__ h, const int* __restrict__ idx_list,
                             const float* __restrict__ val_list, float* __restrict__ out_newh,
                             const int* __restrict__ ei0, const int* __restrict__ ei1,
                             int* __restrict__ cursor, const int* __restrict__ rank,
                             int* __restrict__ nbr, int* __restrict__ deg2,
                             int kN, int E) {
    int b = blockIdx.x, tid = threadIdx.x;
    int nnewh = kN >> 2;                        // 4 waves/block
    if (b < nnewh) {
        int wave = (b << 2) + (tid >> 6);
        int lane = tid & 63;
        int i = idx_list[wave];
        float v = val_list[wave];
        float4 a = ((const float4*)(h + (size_t)i * 256))[lane];
        nt_store4(out_newh + (size_t)wave * 256 + lane * 4,
                  a.x * v, a.y * v, a.z * v, a.w * v);
    } else {
        int e = ((b - nnewh) << 8) + tid;
        if (e < E) {
            int u = ei0[e], v = ei1[e];
            int p = atomicAdd(&cursor[u], 1);
            nbr[p] = v;
            if (rank[v] < kN) atomicAdd(&deg2[u], 1);   // u's selected out-targets
        }
    }
}

// ---- node5: block0 = scan2(deg2 -> offs2,cursor2); blocks 1.. = rowlen ----
// rowlen[r] = sum of deg2 over first-hop nbrs of selected node r (wave per row).
__global__ void scan2_rowlen(const int* __restrict__ deg2, int* __restrict__ offs2,
                             int* __restrict__ cursor2, const int* __restrict__ idx_list,
                             const int* __restrict__ offs, const int* __restrict__ nbr,
                             int* __restrict__ rowlen, int N, int kN) {
    __shared__ int part[1024];
    int b = blockIdx.x, t = threadIdx.x;
    if (b == 0) {
        int per = N >> 10;                      // 8 per thread
        int base = t * per;
        int loc[8];
        int s = 0;
        #pragma unroll
        for (int j = 0; j < 8; ++j) { if (j < per) { loc[j] = s; s += deg2[base + j]; } }
        part[t] = s;
        __syncthreads();
        for (int d = 1; d < 1024; d <<= 1) {
            int v = (t >= d) ? part[t - d] : 0;
            __syncthreads();
            part[t] += v;
            __syncthreads();
        }
        int excl = (t == 0) ? 0 : part[t - 1];
        #pragma unroll
        for (int j = 0; j < 8; ++j) {
            if (j < per) { int o = excl + loc[j]; offs2[base + j] = o; cursor2[base + j] = o; }
        }
        if (t == 1023) offs2[N] = part[1023];
    } else {
        int wid = t >> 6, lane = t & 63;
        int r = (b - 1) * 16 + wid;             // 16 waves per 1024-thr block
        if (r < kN) {
            int u = idx_list[r];
            int s0 = offs[u], s1 = offs[u + 1];
            int sum = 0;
            for (int j = s0 + lane; j < s1; j += 64) sum += deg2[nbr[j]];
            #pragma unroll
            for (int off = 32; off; off >>= 1) sum += __shfl_xor(sum, off);
            if (lane == 0) rowlen[r] = sum;
        }
    }
}

// ---- node6: block0 = scan3(rowlen -> rowoff,rowcur); blocks 1.. = scatter2 ----
__global__ void scan3_scatter2(const int* __restrict__ rowlen, int* __restrict__ rowoff,
                               int* __restrict__ rowcur, const int* __restrict__ ei0,
                               const int* __restrict__ ei1, const int* __restrict__ rank,
                               int* __restrict__ cursor2, int* __restrict__ nbr2,
                               int E, int kN) {
    __shared__ int part[1024];
    int b = blockIdx.x, t = threadIdx.x;
    if (b == 0) {
        int per = kN >> 10;                     // 4 per thread (kN=4096)
        int base = t * per;
        int loc[4];
        int s = 0;
        #pragma unroll
        for (int j = 0; j < 4; ++j) { if (j < per) { loc[j] = s; s += rowlen[base + j]; } }
        part[t] = s;
        __syncthreads();
        for (int d = 1; d < 1024; d <<= 1) {
            int v = (t >= d) ? part[t - d] : 0;
            __syncthreads();
            part[t] += v;
            __syncthreads();
        }
        int excl = (t == 0) ? 0 : part[t - 1];
        #pragma unroll
        for (int j = 0; j < 4; ++j) {
            if (j < per) { int o = excl + loc[j]; rowoff[base + j] = o; rowcur[base + j] = o; }
        }
    } else {
        int e = (b - 1) * 1024 + t;
        if (e < E) {
            int r = rank[ei1[e]];
            if (r < kN) {
                int pos = atomicAdd(&cursor2[ei0[e]], 1);
                nbr2[pos] = r;
            }
        }
    }
}

// ---- node7: copy — for each first-hop edge with selected source, append the
// target's filtered rank segment (contiguous) into the source row's region ----
__global__ void copy_rowlist(const int* __restrict__ ei0, const int* __restrict__ ei1,
                             const int* __restrict__ rank, const int* __restrict__ offs2,
                             const int* __restrict__ deg2, const int* __restrict__ nbr2,
                             int* __restrict__ rowcur, int* __restrict__ rowlist, int E, int kN) {
    int e = blockIdx.x * blockDim.x + threadIdx.x;
    if (e >= E) return;
    int r = rank[ei0[e]];
    if (r >= kN) return;
    int v = ei1[e];
    int L = deg2[v];
    if (L == 0) return;
    int pos = atomicAdd(&rowcur[r], L);
    int s = offs2[v];
    #pragma unroll 4
    for (int j = 0; j < L; ++j) rowlist[pos + j] = nbr2[s + j];   // contiguous both sides
}

// ---- node8: stream-paths — coalesced rowlist stream -> LDS atomics -> store ----
__global__ void paths_stream(const int* __restrict__ rowoff, const int* __restrict__ rowlen,
                             const int* __restrict__ rowlist, float* __restrict__ ung, int kN) {
    extern __shared__ float row[];              // kN floats
    int tid = threadIdx.x;
    int r = blockIdx.x;
    float4* row4 = (float4*)row;
    float4 z4 = make_float4(0.f, 0.f, 0.f, 0.f);
    for (int i = tid; i < (kN >> 2); i += 256) row4[i] = z4;
    __syncthreads();
    int base = rowoff[r];
    int len = rowlen[r];
    for (int i = tid; i < len; i += 256)
        atomicAdd(&row[rowlist[base + i]], 1.0f);   // coalesced load, no chains
    __syncthreads();
    float* dst = ung + (size_t)r * kN;
    for (int i = tid; i < (kN >> 2); i += 256) {
        float4 v = row4[i];
        nt_store4(dst + (size_t)i * 4, v.x, v.y, v.z, v.w);
    }
}

extern "C" void kernel_launch(void* const* d_in, const int* in_sizes, int n_in,
                              void* d_out, int out_size, void* d_ws, size_t ws_size,
                              hipStream_t stream) {
    const float* h = (const float*)d_in[0];
    const int* ei = (const int*)d_in[1];            // [2,E] flat: ei0 = ei, ei1 = ei+E
    const int* batch = (const int*)d_in[3];
    const float* pw = (const float*)d_in[4];
    const float* pb = (const float*)d_in[5];

    int N = in_sizes[3];        // 8192
    int E = in_sizes[1] / 2;    // 262144
    int kN = N / 2;
    if (kN < 2) kN = 2;

    float* out = (float*)d_out;
    float* out_newh = out;                              // kN*256
    float* out_ung = out_newh + (size_t)kN * 256;       // kN*kN
    float* out_ea = out_ung + (size_t)kN * kN;          // E
    float* out_nb = out_ea + E;                         // kN
    float* out_idx = out_nb + kN;                       // kN

    char* ws = (char*)d_ws;
    u64* keys    = (u64*)(ws + 0);          // 64 KB
    int* rankcnt = (int*)(ws + 65536);      // 32 KB (zeroed in node1 with deg, deg2)
    int* deg     = (int*)(ws + 98304);      // 32 KB
    int* deg2    = (int*)(ws + 131072);     // 32 KB
    int* idx_list= (int*)(ws + 163840);     // 16 KB
    float* vals  = (float*)(ws + 180224);   // 16 KB
    int* rank    = (int*)(ws + 196608);     // 32 KB
    int* offs    = (int*)(ws + 229376);     // 32 KB + 4 (pad to 262656)
    int* cursor  = (int*)(ws + 262656);     // 32 KB
    int* offs2   = (int*)(ws + 295424);     // 32 KB + 4 (pad to 328704)
    int* cursor2 = (int*)(ws + 328704);     // 32 KB
    int* rowlen  = (int*)(ws + 361472);     // 16 KB
    int* rowoff  = (int*)(ws + 377856);     // 16 KB
    int* rowcur  = (int*)(ws + 394240);     // 16 KB
    int* nbr     = (int*)(ws + 410624);     // 1 MB
    int* nbr2    = (int*)(ws + 1459200);    // 1 MB
    int* rowlist = (int*)(ws + 2507776);    // up to 64 MB (expected ~8.4 MB)

    // node1: scores + zero(rankcnt,deg,deg2) + ones(edge_attr)
    fused_scores<<<(N * 64 + 255) / 256, 256, 0, stream>>>(h, pw, pb, keys, rankcnt,
                                                           out_ea, N, E / 4);
    // node2: rank counting + first-hop degree histogram
    int nrank = (N >> 10) * (N >> 8);
    int nhist = (E + 1023) / 1024;
    rank_hist<<<nrank + nhist, 256, 0, stream>>>(keys, rankcnt, ei, deg, N, E, nrank);
    // node3: select + scan(deg -> offs,cursor)
    select_scan<<<(N >> 10) + 1, 1024, 0, stream>>>(keys, rankcnt, batch, idx_list, vals,
                                                    rank, out_idx, out_nb, deg, offs,
                                                    cursor, N, kN);
    // node4: new_h + scatter1(nbr) + hist2(deg2)
    newh_scatter<<<(kN >> 2) + (E >> 8), 256, 0, stream>>>(h, idx_list, vals, out_newh,
                                                           ei, ei + E, cursor, rank,
                                                           nbr, deg2, kN, E);
    // node5: scan2(offs2,cursor2) + rowlen (wave per selected row)
    int nrl = (kN + 15) / 16;                   // 1024-thr blocks, 16 waves each
    scan2_rowlen<<<1 + nrl, 1024, 0, stream>>>(deg2, offs2, cursor2, idx_list, offs,
                                               nbr, rowlen, N, kN);
    // node6: scan3(rowoff,rowcur) + scatter2(nbr2)
    scan3_scatter2<<<1 + (E + 1023) / 1024, 1024, 0, stream>>>(rowlen, rowoff, rowcur,
                                                               ei, ei + E, rank, cursor2,
                                                               nbr2, E, kN);
    // node7: copy rowlist (edge-parallel, contiguous segment copy)
    copy_rowlist<<<(E + 255) / 256, 256, 0, stream>>>(ei, ei + E, rank, offs2, deg2,
                                                      nbr2, rowcur, rowlist, E, kN);
    // node8: stream-paths (coalesced rowlist -> LDS atomics -> store)
    paths_stream<<<kN, 256, (size_t)kN * 4, stream>>>(rowoff, rowlen, rowlist,
                                                      out_ung, kN);
}

// Round 17
// 83.375 us; speedup vs baseline: 1.4084x; 1.4084x over previous
//
#include <hip/hip_runtime.h>

// GraphUnetPool: scores = sigmoid(h@w+b); top-k (k=N/2) by exact rank-count;
// new_h = h[idx]*values; un_g = (g@g)[idx][:,idx] via per-row LDS 2-path counting.
// R17 = R10 structure; paths inner loop: 16-deep ILP gather + discard-filtered
// LDS atomics (no row[kN] same-address pile-up).

typedef unsigned long long u64;
typedef unsigned int u32;
typedef float f32x4 __attribute__((ext_vector_type(4)));   // native vec for nt-store

__device__ __forceinline__ void nt_store4(float* p, float x, float y, float z, float w) {
    f32x4 v = { x, y, z, w };
    __builtin_nontemporal_store(v, (f32x4*)p);
}

// ---- node1: scores (1 wave/row) + zero rankcnt/deg + edge_attr ones ----
__global__ void fused_scores(const float* __restrict__ h, const float* __restrict__ w,
                             const float* __restrict__ b, u64* __restrict__ keys,
                             int* __restrict__ zerobuf, float* __restrict__ ones_out,
                             int N, int n4) {
    int g = blockIdx.x * blockDim.x + threadIdx.x;
    if (g < 2 * N) zerobuf[g] = 0;              // rankcnt (N) + deg (N), adjacent
    if (g < n4) nt_store4(ones_out + (size_t)g * 4, 1.f, 1.f, 1.f, 1.f);
    int wave = g >> 6;
    int lane = threadIdx.x & 63;
    if (wave >= N) return;
    const float4 a = ((const float4*)(h + (size_t)wave * 256))[lane];
    const float4 c = ((const float4*)w)[lane];
    float s = a.x * c.x + a.y * c.y + a.z * c.z + a.w * c.w;
    #pragma unroll
    for (int off = 32; off; off >>= 1) s += __shfl_xor(s, off);
    if (lane == 0) {
        s += b[0];
        float sc = 1.0f / (1.0f + expf(-s));
        keys[wave] = ((u64)__float_as_uint(sc) << 32) | (u32)(~wave);  // ties: lower idx
    }
}

// ---- node2: rank (1024-key LDS tiles, 1 elem/thread) + degree hist ----
__global__ void rank_hist(const u64* __restrict__ keys, int* __restrict__ rankcnt,
                          const int* __restrict__ ei0, int* __restrict__ deg,
                          int N, int E, int nrank) {
    __shared__ u64 lk[1024];
    int b = blockIdx.x, tid = threadIdx.x;
    if (b < nrank) {
        int ngroups = N >> 8;                   // element groups of 256
        int chunk = b / ngroups;                // 1024-key chunks
        int elg = b % ngroups;
        int base = chunk << 10;
        #pragma unroll
        for (int j = 0; j < 4; ++j) lk[tid + (j << 8)] = keys[base + tid + (j << 8)];
        __syncthreads();
        int el = (elg << 8) + tid;
        u64 mk = keys[el];
        int cnt = 0;
        #pragma unroll 16
        for (int i = 0; i < 1024; ++i) cnt += (lk[i] > mk) ? 1 : 0;
        atomicAdd(&rankcnt[el], cnt);
    } else {
        int e0 = ((b - nrank) << 10) + tid;     // 4 edges/thread
        #pragma unroll
        for (int j = 0; j < 4; ++j) {
            int e = e0 + (j << 8);
            if (e < E) atomicAdd(&deg[ei0[e]], 1);
        }
    }
}

// ---- node3: select (rank scatter, outputs idx/batch) + CSR exclusive scan ----
__global__ void select_scan(const u64* __restrict__ keys, const int* __restrict__ rankcnt,
                            const int* __restrict__ batch, int* __restrict__ idx_list,
                            float* __restrict__ val_list, int* __restrict__ rank,
                            float* __restrict__ out_idx, float* __restrict__ out_batch,
                            const int* __restrict__ deg, int* __restrict__ offs,
                            int* __restrict__ cursor, int N, int kN) {
    __shared__ int part[1024];
    int b = blockIdx.x, t = threadIdx.x;
    int nsel = N >> 10;                         // select blocks (1024 thr each)
    if (b < nsel) {
        int i = (b << 10) + t;
        int r = rankcnt[i];
        rank[i] = (r < kN) ? r : kN;            // kN = discard marker
        if (r < kN) {
            idx_list[r] = i;
            val_list[r] = __uint_as_float((u32)(keys[i] >> 32));
            out_idx[r] = (float)i;
            out_batch[r] = (float)batch[i];
        }
    } else {
        int per = N >> 10;                      // 8 per thread
        int base = t * per;
        int loc[8];
        int s = 0;
        #pragma unroll
        for (int j = 0; j < 8; ++j) { if (j < per) { loc[j] = s; s += deg[base + j]; } }
        part[t] = s;
        __syncthreads();
        for (int d = 1; d < 1024; d <<= 1) {
            int v = (t >= d) ? part[t - d] : 0;
            __syncthreads();
            part[t] += v;
            __syncthreads();
        }
        int excl = (t == 0) ? 0 : part[t - 1];
        #pragma unroll
        for (int j = 0; j < 8; ++j) {
            if (j < per) { int o = excl + loc[j]; offs[base + j] = o; cursor[base + j] = o; }
        }
        if (t == 1023) offs[N] = part[1023];
    }
}

// ---- node4: new_h + scatter with packed 2-hop descriptors ----
// Slot p (edge u->v): desc[p] = {offs[v], deg[v]}, nbrrank[p] = rank[v].
__global__ void newh_scatter(const float* __restrict__ h, const int* __restrict__ idx_list,
                             const float* __restrict__ val_list, float* __restrict__ out_newh,
                             const int* __restrict__ ei0, const int* __restrict__ ei1,
                             int* __restrict__ cursor, const int* __restrict__ offs,
                             const int* __restrict__ deg, const int* __restrict__ rank,
                             int2* __restrict__ desc, int* __restrict__ nbrrank,
                             int kN, int E) {
    int b = blockIdx.x, tid = threadIdx.x;
    int nnewh = kN >> 2;                        // 4 waves/block
    if (b < nnewh) {
        int wave = (b << 2) + (tid >> 6);
        int lane = tid & 63;
        int i = idx_list[wave];
        float v = val_list[wave];
        float4 a = ((const float4*)(h + (size_t)i * 256))[lane];
        nt_store4(out_newh + (size_t)wave * 256 + lane * 4,
                  a.x * v, a.y * v, a.z * v, a.w * v);
    } else {
        int e = ((b - nnewh) << 8) + tid;
        if (e < E) {
            int u = ei0[e], v = ei1[e];
            int p = atomicAdd(&cursor[u], 1);
            desc[p] = make_int2(offs[v], deg[v]);
            nbrrank[p] = rank[v];
        }
    }
}

// ---- node5: 2-path accumulation; wave per segment; 16-deep ILP gather;
//      discard-filtered LDS atomics ----
__global__ void paths_row_kernel(const int* __restrict__ idx_list, const int* __restrict__ offs,
                                 const int2* __restrict__ desc, const int* __restrict__ nbrrank,
                                 float* __restrict__ ung, int kN) {
    extern __shared__ float row[];              // kN floats; then toff[256], tlen[256]
    int* toff = (int*)(row + kN);
    int* tlen = toff + 256;
    int tid = threadIdx.x;
    float4* row4 = (float4*)row;
    float4 z4 = make_float4(0.f, 0.f, 0.f, 0.f);
    for (int i = tid; i < (kN >> 2); i += 256) row4[i] = z4;
    __syncthreads();
    int u = idx_list[blockIdx.x];
    int s0 = offs[u], s1 = offs[u + 1];
    int nf = s1 - s0;
    int wid = tid >> 6;                         // wave 0..3
    int lane = tid & 63;
    for (int fb = 0; fb < nf; fb += 256) {
        int nt = min(256, nf - fb);
        if (tid < nt) {
            int2 dd = desc[s0 + fb + tid];      // coalesced 8B descriptor stage
            toff[tid] = dd.x; tlen[tid] = dd.y;
        }
        __syncthreads();
        // wave per segment, 16 segments per wave: issue ALL 16 gathers (independent,
        // coalesced), THEN the atomics; skip discard ranks (va == kN).
        for (int f0 = wid; f0 < nt; f0 += 256) {
            int va[16];
            #pragma unroll
            for (int k = 0; k < 16; ++k) {
                int f = f0 + (k << 2);
                va[k] = kN;
                if (f < nt) {
                    int t0 = toff[f], L = tlen[f];
                    if (lane < L) va[k] = nbrrank[t0 + lane];
                }
            }
            #pragma unroll
            for (int k = 0; k < 16; ++k)
                if (va[k] < kN) atomicAdd(&row[va[k]], 1.0f);
            #pragma unroll
            for (int k = 0; k < 16; ++k) {      // rare tail: deg > 64
                int f = f0 + (k << 2);
                if (f < nt) {
                    int t0 = toff[f], L = tlen[f];
                    for (int q = lane + 64; q < L; q += 64) {
                        int r = nbrrank[t0 + q];
                        if (r < kN) atomicAdd(&row[r], 1.0f);
                    }
                }
            }
        }
        __syncthreads();
    }
    float* dst = ung + (size_t)blockIdx.x * kN;
    for (int i = tid; i < (kN >> 2); i += 256) {
        float4 v = row4[i];
        nt_store4(dst + (size_t)i * 4, v.x, v.y, v.z, v.w);   // don't evict gather set
    }
}

extern "C" void kernel_launch(void* const* d_in, const int* in_sizes, int n_in,
                              void* d_out, int out_size, void* d_ws, size_t ws_size,
                              hipStream_t stream) {
    const float* h = (const float*)d_in[0];
    const int* ei = (const int*)d_in[1];            // [2,E] flat: ei0 = ei, ei1 = ei+E
    const int* batch = (const int*)d_in[3];
    const float* pw = (const float*)d_in[4];
    const float* pb = (const float*)d_in[5];

    int N = in_sizes[3];        // 8192
    int E = in_sizes[1] / 2;    // 262144
    int kN = N / 2;
    if (kN < 2) kN = 2;

    float* out = (float*)d_out;
    float* out_newh = out;                              // kN*256
    float* out_ung = out_newh + (size_t)kN * 256;       // kN*kN
    float* out_ea = out_ung + (size_t)kN * kN;          // E
    float* out_nb = out_ea + E;                         // kN
    float* out_idx = out_nb + kN;                       // kN

    char* ws = (char*)d_ws;
    u64* keys    = (u64*)(ws + 0);          // 64 KB
    int* rankcnt = (int*)(ws + 65536);      // 32 KB (zeroed in node1 with deg)
    int* deg     = (int*)(ws + 98304);      // 32 KB
    int* idx_list= (int*)(ws + 131072);     // 16 KB
    float* vals  = (float*)(ws + 147456);   // 16 KB
    int* rank    = (int*)(ws + 163840);     // 32 KB
    int* offs    = (int*)(ws + 196608);     // 32 KB + 4
    int* cursor  = (int*)(ws + 229632);     // 32 KB
    int2* desc   = (int2*)(ws + 262400);    // 2 MB
    int* nbrrank = (int*)(ws + 2359552);    // 1 MB

    // node1: scores + zero(rankcnt,deg) + ones(edge_attr)
    fused_scores<<<(N * 64 + 255) / 256, 256, 0, stream>>>(h, pw, pb, keys, rankcnt,
                                                           out_ea, N, E / 4);
    // node2: rank counting (1024-key LDS tiles, 1 elem/thread) + degree histogram
    int nrank = (N >> 10) * (N >> 8);
    int nhist = (E + 1023) / 1024;
    rank_hist<<<nrank + nhist, 256, 0, stream>>>(keys, rankcnt, ei, deg, N, E, nrank);
    // node3: select + scan
    select_scan<<<(N >> 10) + 1, 1024, 0, stream>>>(keys, rankcnt, batch, idx_list, vals,
                                                    rank, out_idx, out_nb, deg, offs,
                                                    cursor, N, kN);
    // node4: new_h + scatter with packed 2-hop descriptors
    newh_scatter<<<(kN >> 2) + (E >> 8), 256, 0, stream>>>(h, idx_list, vals, out_newh,
                                                           ei, ei + E, cursor, offs, deg,
                                                           rank, desc, nbrrank, kN, E);
    // node5: per-row 2-path accumulation (ILP gather + filtered atomics)
    paths_row_kernel<<<kN, 256, (size_t)kN * 4 + 2048, stream>>>(idx_list, offs, desc,
                                                                 nbrrank, out_ung, kN);
}